// Round 4
// baseline (412.397 us; speedup 1.0000x reference)
//
#include <hip/hip_runtime.h>
#include <hip/hip_bf16.h>

#define NEDGE 800000
#define NNODE 50000
#define DF    64
#define HID   128
#define NTILE (NEDGE / 16)
#define EOUT_ELEMS ((size_t)NEDGE * 128)

using short8 = __attribute__((ext_vector_type(8))) short;
using f32x4  = __attribute__((ext_vector_type(4))) float;
using i32x4  = __attribute__((ext_vector_type(4))) int;

union P8 { unsigned int u[4]; short8 s; };

__device__ __forceinline__ unsigned int pk2(float lo, float hi) {
    union { __hip_bfloat162 p; unsigned int u; } c;
    c.p = __float22bfloat162_rn(float2{lo, hi});
    return c.u;
}

__device__ __forceinline__ short8 cvt8(f32x4 u, f32x4 v) {
    P8 p;
    p.u[0] = pk2(u[0], u[1]);
    p.u[1] = pk2(u[2], u[3]);
    p.u[2] = pk2(v[0], v[1]);
    p.u[3] = pk2(v[2], v[3]);
    return p.s;
}

__device__ __forceinline__ unsigned short bf1(float f) {
    union { __hip_bfloat16 b; unsigned short u; } c;
    c.b = __float2bfloat16(f);
    return c.u;
}

__device__ __forceinline__ float silu_f(float v) {
    return v / (1.0f + __expf(-v));
}

// XOR-swizzled byte offset inside a row-major [R][128]-bf16 tile (row stride 256B).
__device__ __forceinline__ int swz(int r, int k) {
    return (r << 8) + ((((k >> 3) ^ (r & 7)) << 4) | ((k & 7) << 1));
}
__device__ __forceinline__ int swz16(int r, int slot) {
    return (r << 8) + ((slot ^ (r & 7)) << 4);
}

// ============================ CSR build =================================
__global__ void __launch_bounds__(256) hist_kernel(const int* __restrict__ ei,
                                                   int* __restrict__ counts) {
    const int i = blockIdx.x * 256 + threadIdx.x;
    if (i < 2 * NEDGE) atomicAdd(&counts[ei[i]], 1);
}

__global__ void __launch_bounds__(1024) scan_kernel(const int* __restrict__ counts,
                                                    int* __restrict__ offs) {
    __shared__ int buf[1024];
    const int tid = threadIdx.x;
    int carry = 0;
    for (int base = 0; base < NNODE; base += 1024) {
        const int idx = base + tid;
        const int v = (idx < NNODE) ? counts[idx] : 0;
        buf[tid] = v;
        __syncthreads();
#pragma unroll
        for (int off = 1; off < 1024; off <<= 1) {
            const int u = (tid >= off) ? buf[tid - off] : 0;
            __syncthreads();
            buf[tid] += u;
            __syncthreads();
        }
        if (idx < NNODE) offs[idx] = carry + buf[tid] - v;   // exclusive
        carry += buf[1023];
        __syncthreads();
    }
    if (tid == 0) offs[NNODE] = carry;
}

__global__ void __launch_bounds__(256) fill_kernel(const int* __restrict__ ei,
                                                   const int* __restrict__ offs,
                                                   int* __restrict__ cursor,
                                                   int* __restrict__ entries) {
    const int i = blockIdx.x * 256 + threadIdx.x;
    if (i < 2 * NEDGE) {
        const int node = ei[i];
        const int pos = atomicAdd(&cursor[node], 1);
        entries[offs[node] + pos] = i;   // i encodes edge + side (i>=NEDGE -> tgt half)
    }
}

// ==================== Pass 1: edge MLP -> eout (no atomics) ====================
__global__ void __launch_bounds__(256, 2)
gnn_mlp(const float* __restrict__ x, const int* __restrict__ ei,
        const float* __restrict__ t,
        const float* __restrict__ W1, const float* __restrict__ b1,
        const float* __restrict__ Wt, const float* __restrict__ bt,
        const float* __restrict__ W2, const float* __restrict__ b2,
        float* __restrict__ eout)
{
    extern __shared__ char lds[];
    char* const w1s = lds;
    char* const w2s = lds + 32768;
    const int tid  = threadIdx.x;
    const int wave = tid >> 6;
    const int lane = tid & 63;
    char* const hs = lds + 65536 + (wave << 12);

    for (int idx = tid; idx < HID * HID; idx += 256) {
        const int k = idx >> 7, j = idx & 127;
        const int off = swz(j, k);
        *(unsigned short*)(w1s + off) = bf1(W1[idx]);
        *(unsigned short*)(w2s + off) = bf1(W2[idx]);
    }

    const int jl   = lane & 15;
    const int quad = lane >> 4;
    const int k0   = quad << 3;
    float wtj[8], btj[8], b1j[8], b2j[8];
#pragma unroll
    for (int nt = 0; nt < 8; nt++) {
        const int j = nt * 16 + jl;
        wtj[nt] = Wt[j]; btj[nt] = bt[j]; b1j[nt] = b1[j]; b2j[nt] = b2[j];
    }
    __syncthreads();

    const int gwave = (blockIdx.x << 2) + wave;
    const int nwave = gridDim.x << 2;

#define ISSUE_EI(T, RA, CA) { const int e_ = (T) * 16 + jl; RA = ei[e_]; CA = ei[NEDGE + e_]; }
#define ISSUE_X(RA, CA, X_) { \
    const float* xr_ = x + (RA) * DF + k0; \
    const float* xc_ = x + (CA) * DF + k0; \
    X_[0] = *(const f32x4*)(xr_);      X_[1] = *(const f32x4*)(xr_ + 4);  \
    X_[2] = *(const f32x4*)(xr_ + 32); X_[3] = *(const f32x4*)(xr_ + 36); \
    X_[4] = *(const f32x4*)(xc_);      X_[5] = *(const f32x4*)(xc_ + 4);  \
    X_[6] = *(const f32x4*)(xc_ + 32); X_[7] = *(const f32x4*)(xc_ + 36); }

    int tile = gwave;
    int riA, ciA;  ISSUE_EI(tile, riA, ciA);
    f32x4 X[8];    ISSUE_X(riA, ciA, X);
    f32x4 T4 = *(const f32x4*)(t + tile * 16 + (quad << 2));
    int tn  = tile + nwave;
    int tns = (tn < NTILE) ? tn : gwave;
    int riA_n, ciA_n; ISSUE_EI(tns, riA_n, ciA_n);

    while (tile < NTILE) {
        f32x4 Xn[8]; ISSUE_X(riA_n, ciA_n, Xn);
        const f32x4 T4n = *(const f32x4*)(t + tns * 16 + (quad << 2));
        const int t2  = tn + nwave;
        const int t2s = (t2 < NTILE) ? t2 : gwave;
        int riA_nn, ciA_nn; ISSUE_EI(t2s, riA_nn, ciA_nn);

        short8 a[4];
#pragma unroll
        for (int kk = 0; kk < 4; kk++) a[kk] = cvt8(X[2 * kk], X[2 * kk + 1]);

        // ---- GEMM1
#pragma unroll
        for (int nt = 0; nt < 8; nt++) {
            f32x4 acc = {0.f, 0.f, 0.f, 0.f};
            const int j = nt * 16 + jl;
#pragma unroll
            for (int kk = 0; kk < 4; kk++) {
                const short8 bfr = *(const short8*)(w1s + swz16(j, (kk << 2) + quad));
                acc = __builtin_amdgcn_mfma_f32_16x16x32_bf16(a[kk], bfr, acc, 0, 0, 0);
            }
#pragma unroll
            for (int r = 0; r < 4; r++) {
                const float temb = silu_f(fmaf(T4[r], wtj[nt], btj[nt]));
                const float h = silu_f(acc[r] + temb + b1j[nt]);
                *(unsigned short*)(hs + swz((quad << 2) + r, j)) = bf1(h);
            }
        }

        short8 a2[4];
#pragma unroll
        for (int kk = 0; kk < 4; kk++) {
            a2[kk] = *(const short8*)(hs + swz16(jl, (kk << 2) + quad));
        }

        // ---- GEMM2 + bias -> linear coalesced store to eout
        float* const ep = eout + (size_t)(tile * 16 + (quad << 2)) * 128 + jl;
#pragma unroll
        for (int nt = 0; nt < 8; nt++) {
            f32x4 acc = {0.f, 0.f, 0.f, 0.f};
            const int j = nt * 16 + jl;
#pragma unroll
            for (int kk = 0; kk < 4; kk++) {
                const short8 bfr = *(const short8*)(w2s + swz16(j, (kk << 2) + quad));
                acc = __builtin_amdgcn_mfma_f32_16x16x32_bf16(a2[kk], bfr, acc, 0, 0, 0);
            }
#pragma unroll
            for (int r = 0; r < 4; r++) {
                ep[r * 128 + nt * 16] = acc[r] + b2j[nt];
            }
        }

        tile = tn; tn = t2; tns = t2s;
#pragma unroll
        for (int i = 0; i < 8; i++) X[i] = Xn[i];
        T4 = T4n;
        riA_n = riA_nn; ciA_n = ciA_nn;
    }
#undef ISSUE_EI
#undef ISSUE_X
}

// ==================== Pass 2: per-node gather (one wave per node) ================
__global__ void __launch_bounds__(256) gather_kernel(const float* __restrict__ eout,
                                                     const int* __restrict__ offs,
                                                     const int* __restrict__ entries,
                                                     float* __restrict__ out)
{
    const int wave = threadIdx.x >> 6;
    const int lane = threadIdx.x & 63;
    const int n = blockIdx.x * 4 + wave;
    if (n >= NNODE) return;
    const int o0 = offs[n], o1 = offs[n + 1];
    float acc = 0.f;
    int k = o0;
    int ent = (k < o1) ? entries[k] : 0;
    while (k < o1) {
        const int entn = (k + 1 < o1) ? entries[k + 1] : 0;
        const int side = (ent >= NEDGE) ? 1 : 0;
        const int e = ent - side * NEDGE;
        acc += eout[(size_t)e * 128 + side * 64 + lane];
        ent = entn;
        ++k;
    }
    out[(size_t)n * 64 + lane] = acc;
}

// ==================== Fallback: fused atomic version (R3 kernel) ================
__global__ void __launch_bounds__(256, 2)
gnn_fused_atomic(const float* __restrict__ x, const int* __restrict__ ei,
                 const float* __restrict__ t,
                 const float* __restrict__ W1, const float* __restrict__ b1,
                 const float* __restrict__ Wt, const float* __restrict__ bt,
                 const float* __restrict__ W2, const float* __restrict__ b2,
                 float* __restrict__ out)
{
    extern __shared__ char lds[];
    char* const w1s = lds;
    char* const w2s = lds + 32768;
    const int tid  = threadIdx.x;
    const int wave = tid >> 6;
    const int lane = tid & 63;
    char* const hs = lds + 65536 + (wave << 12);

    for (int idx = tid; idx < HID * HID; idx += 256) {
        const int k = idx >> 7, j = idx & 127;
        const int off = swz(j, k);
        *(unsigned short*)(w1s + off) = bf1(W1[idx]);
        *(unsigned short*)(w2s + off) = bf1(W2[idx]);
    }

    const int jl   = lane & 15;
    const int quad = lane >> 4;
    const int k0   = quad << 3;
    float wtj[8], btj[8], b1j[8], b2j[8];
#pragma unroll
    for (int nt = 0; nt < 8; nt++) {
        const int j = nt * 16 + jl;
        wtj[nt] = Wt[j]; btj[nt] = bt[j]; b1j[nt] = b1[j]; b2j[nt] = b2[j];
    }
    __syncthreads();

    const int gwave = (blockIdx.x << 2) + wave;
    const int nwave = gridDim.x << 2;

    for (int tile = gwave; tile < NTILE; tile += nwave) {
        const int base = tile << 4;
        const int eA = base + jl;
        const int ri = ei[eA];
        const int ci = ei[NEDGE + eA];

        short8 a[4];
        {
            const float* xr_ = x + ri * DF + k0;
            const float* xc_ = x + ci * DF + k0;
            a[0] = cvt8(*(const f32x4*)(xr_),      *(const f32x4*)(xr_ + 4));
            a[1] = cvt8(*(const f32x4*)(xr_ + 32), *(const f32x4*)(xr_ + 36));
            a[2] = cvt8(*(const f32x4*)(xc_),      *(const f32x4*)(xc_ + 4));
            a[3] = cvt8(*(const f32x4*)(xc_ + 32), *(const f32x4*)(xc_ + 36));
        }

        const int er = base + (quad << 2);
        const f32x4 T4 = *(const f32x4*)(t + er);
        const i32x4 RI = *(const i32x4*)(ei + er);
        const i32x4 CI = *(const i32x4*)(ei + NEDGE + er);

#pragma unroll
        for (int nt = 0; nt < 8; nt++) {
            f32x4 acc = {0.f, 0.f, 0.f, 0.f};
            const int j = nt * 16 + jl;
#pragma unroll
            for (int kk = 0; kk < 4; kk++) {
                const short8 bfr = *(const short8*)(w1s + swz16(j, (kk << 2) + quad));
                acc = __builtin_amdgcn_mfma_f32_16x16x32_bf16(a[kk], bfr, acc, 0, 0, 0);
            }
#pragma unroll
            for (int r = 0; r < 4; r++) {
                const float temb = silu_f(fmaf(T4[r], wtj[nt], btj[nt]));
                const float h = silu_f(acc[r] + temb + b1j[nt]);
                *(unsigned short*)(hs + swz((quad << 2) + r, j)) = bf1(h);
            }
        }

        short8 a2[4];
#pragma unroll
        for (int kk = 0; kk < 4; kk++) {
            a2[kk] = *(const short8*)(hs + swz16(jl, (kk << 2) + quad));
        }

#pragma unroll
        for (int nt = 0; nt < 8; nt++) {
            f32x4 acc = {0.f, 0.f, 0.f, 0.f};
            const int j = nt * 16 + jl;
#pragma unroll
            for (int kk = 0; kk < 4; kk++) {
                const short8 bfr = *(const short8*)(w2s + swz16(j, (kk << 2) + quad));
                acc = __builtin_amdgcn_mfma_f32_16x16x32_bf16(a2[kk], bfr, acc, 0, 0, 0);
            }
#pragma unroll
            for (int r = 0; r < 4; r++) {
                const float v = acc[r] + b2j[nt];
                const int node = (nt < 4) ? RI[r] : CI[r];
                unsafeAtomicAdd(out + node * DF + (j & 63), v);
            }
        }
    }
}

extern "C" void kernel_launch(void* const* d_in, const int* in_sizes, int n_in,
                              void* d_out, int out_size, void* d_ws, size_t ws_size,
                              hipStream_t stream) {
    const float* x  = (const float*)d_in[0];
    const int*   ei = (const int*)d_in[1];
    const float* t  = (const float*)d_in[2];
    const float* W1 = (const float*)d_in[3];
    const float* b1 = (const float*)d_in[4];
    const float* Wt = (const float*)d_in[5];
    const float* bt = (const float*)d_in[6];
    const float* W2 = (const float*)d_in[7];
    const float* b2 = (const float*)d_in[8];
    float* out = (float*)d_out;

    const size_t EOUT_B = EOUT_ELEMS * sizeof(float);                 // 409.6 MB
    const size_t csr_ints = (size_t)NNODE * 3 + 1 + 2 * (size_t)NEDGE;
    const size_t need = EOUT_B + csr_ints * sizeof(int);

    const int ldsBytes = 65536 + 4 * 4096;  // 80KB -> 2 blocks/CU

    if (ws_size >= need) {
        char* wsb = (char*)d_ws;
        float* eout   = (float*)wsb;
        int* counts   = (int*)(wsb + EOUT_B);
        int* cursor   = counts + NNODE;
        int* offs     = cursor + NNODE;          // NNODE+1
        int* entries  = offs + NNODE + 1;

        // zero counts + cursor (adjacent, 400 KB)
        (void)hipMemsetAsync(counts, 0, 2 * (size_t)NNODE * sizeof(int), stream);

        hipLaunchKernelGGL(hist_kernel, dim3((2 * NEDGE + 255) / 256), dim3(256), 0, stream,
                           ei, counts);
        hipLaunchKernelGGL(scan_kernel, dim3(1), dim3(1024), 0, stream, counts, offs);
        hipLaunchKernelGGL(fill_kernel, dim3((2 * NEDGE + 255) / 256), dim3(256), 0, stream,
                           ei, offs, cursor, entries);

        (void)hipFuncSetAttribute((const void*)gnn_mlp,
                                  hipFuncAttributeMaxDynamicSharedMemorySize, ldsBytes);
        hipLaunchKernelGGL(gnn_mlp, dim3(512), dim3(256), ldsBytes, stream,
                           x, ei, t, W1, b1, Wt, bt, W2, b2, eout);

        hipLaunchKernelGGL(gather_kernel, dim3((NNODE + 3) / 4), dim3(256), 0, stream,
                           eout, offs, entries, out);
    } else {
        // fallback: fused atomic version
        (void)hipMemsetAsync(out, 0, (size_t)out_size * sizeof(float), stream);
        (void)hipFuncSetAttribute((const void*)gnn_fused_atomic,
                                  hipFuncAttributeMaxDynamicSharedMemorySize, ldsBytes);
        hipLaunchKernelGGL(gnn_fused_atomic, dim3(512), dim3(256), ldsBytes, stream,
                           x, ei, t, W1, b1, Wt, bt, W2, b2, out);
    }
}